// Round 3
// baseline (1433.317 us; speedup 1.0000x reference)
//
#include <hip/hip_runtime.h>

// ---------------------------------------------------------------------------
// MoE forward: gating MLP + 8 dense experts + gate-weighted combine.
// All matmuls via mfma_f32_16x16x32_f16 (fp32 accum).
// GEMM: BM=256, BK=32, FOUR buffers per operand -> prefetch depth 3 tiles
// (issue->wait lead ~2 tile-phases > HBM latency). One phase per K-tile,
// 2 barriers/tile, counted vmcnt drains one stage-point per phase.
// LDS swizzle: XOR within 128B super-rows (off ^= ((row>>1 & 7)<<4)),
// inverse applied to the global source (rule #21: gload_lds writes linearly).
// ---------------------------------------------------------------------------

#define DI __device__ __forceinline__

typedef _Float16 f16;
typedef _Float16 f16x8 __attribute__((ext_vector_type(8)));
typedef float f32x4 __attribute__((ext_vector_type(4)));

constexpr int BSZ  = 8192;
constexpr int IND  = 1024;
constexpr int HID  = 4096;
constexpr int OUTD = 1024;
constexpr int NE   = 8;
constexpr int HGD  = 2048;

// ---------------- fp32 -> fp16 vectorized convert (8 elems/thread) ---------
__global__ __launch_bounds__(256) void conv_f32_f16_kernel(
    const float* __restrict__ in, f16* __restrict__ out)
{
    size_t i = ((size_t)blockIdx.x * 256 + threadIdx.x) * 8;
    const float4* p = (const float4*)(in + i);
    float4 a = p[0], b = p[1];
    f16x8 v = {(f16)a.x, (f16)a.y, (f16)a.z, (f16)a.w,
               (f16)b.x, (f16)b.y, (f16)b.z, (f16)b.w};
    *(f16x8*)(out + i) = v;
}

// ------------- transpose + convert: W[K][N] f32 -> Wt[N][K] f16 ------------
__global__ __launch_bounds__(256) void transpose_f32_f16_kernel(
    const float* __restrict__ W, f16* __restrict__ Wt, int K, int N)
{
    __shared__ float t[64][65];
    int n0 = blockIdx.x * 64, k0 = blockIdx.y * 64;
    int tx = threadIdx.x & 63, ty = threadIdx.x >> 6;
#pragma unroll
    for (int i = 0; i < 16; i++) {
        int k = i * 4 + ty;
        t[k][tx] = W[(size_t)(k0 + k) * N + n0 + tx];
    }
    __syncthreads();
#pragma unroll
    for (int i = 0; i < 16; i++) {
        int n = i * 4 + ty;
        Wt[(size_t)(n0 + n) * K + k0 + tx] = (f16)t[tx][n];
    }
}

// ---------------- async global->LDS (16B per lane, wave-uniform dest) ------
DI void gload_lds16(const void* g, void* l)
{
    typedef const __attribute__((address_space(1))) unsigned int as1_t;
    typedef __attribute__((address_space(3))) unsigned int as3_t;
    __builtin_amdgcn_global_load_lds(
        (as1_t*)(unsigned long long)(__SIZE_TYPE__)g,
        (as3_t*)(unsigned int)(__SIZE_TYPE__)l,
        16, 0, 0);
}

// ---------------------------------------------------------------------------
// 4-buffer GEMM: C[M,N] = op(A[M,K] @ Bt[N,K]^T + bias[N])
// Phase T (tile T, buffer T&3):
//   ds_read all frags of tile T | stage tile T+3 -> buf (T+3)&3
//   barrier ; lgkmcnt(0) ; setprio(1) ; 8xNF MFMA ; setprio(0)
//   vmcnt(counted: drains tile T+1's stage) ; barrier
// Buffer (T+3)&3 was last read at phase T-1 (one barrier earlier) -> safe.
// Steady in-flight: 3 stage points = 12|9 loads -> vmcnt(8|6).
// ---------------------------------------------------------------------------

#define VMAIN { if constexpr (NBC == 2) asm volatile("s_waitcnt vmcnt(8)");   \
                else                     asm volatile("s_waitcnt vmcnt(6)"); }
#define VMTAIL1 { if constexpr (NBC == 2) asm volatile("s_waitcnt vmcnt(4)"); \
                  else                     asm volatile("s_waitcnt vmcnt(3)"); }
#define VMTAIL2 { asm volatile("s_waitcnt vmcnt(0)"); }

#define STG(TT, BB) { stA(BB, 0, TT); stA(BB, 1, TT); stB(BB, 0, TT);         \
                      if constexpr (NBC == 2) stB(BB, 1, TT); }

#define PHASE(B, STAGE, VM)                                                    \
  {                                                                            \
    f16x8 av[8]; f16x8 bv[NF];                                                 \
    _Pragma("unroll") for (int f = 0; f < 8; f++)                              \
        av[f] = *(const f16x8*)(sAc + (B) * 16384 + offA[f]);                  \
    _Pragma("unroll") for (int n = 0; n < NF; n++)                             \
        bv[n] = *(const f16x8*)(sBc + (B) * (BN * 64) + offB[n]);              \
    STAGE                                                                      \
    __builtin_amdgcn_sched_barrier(0);                                         \
    __builtin_amdgcn_s_barrier();                                              \
    asm volatile("s_waitcnt lgkmcnt(0)" ::: "memory");                         \
    __builtin_amdgcn_sched_barrier(0);                                         \
    __builtin_amdgcn_s_setprio(1);                                             \
    _Pragma("unroll") for (int fm = 0; fm < 8; fm++)                           \
      _Pragma("unroll") for (int n = 0; n < NF; n++)                           \
        acc[fm][n] = __builtin_amdgcn_mfma_f32_16x16x32_f16(                   \
            av[fm], bv[n], acc[fm][n], 0, 0, 0);                               \
    __builtin_amdgcn_s_setprio(0);                                             \
    VM                                                                         \
    __builtin_amdgcn_sched_barrier(0);                                         \
    __builtin_amdgcn_s_barrier();                                              \
    asm volatile("" ::: "memory");                                             \
  }

template <int BN, bool RELU, bool GATE, bool OUT_F16, bool ACCUM>
__global__ __launch_bounds__(512, 2) void gemm4b_kernel(
    const f16* __restrict__ A, const f16* __restrict__ Bt,
    const float* __restrict__ bias, const float* __restrict__ gate,
    void* __restrict__ Cptr, int M, int N, int K)
{
    constexpr int BM = 256, BK = 32;
    constexpr int NF  = BN / 64;          // n-frags per wave
    constexpr int NBC = BN / 128;         // B stage calls per tile (2|1)
    __shared__ __align__(16) f16 sA[4][BM * BK];
    __shared__ __align__(16) f16 sB[4][BN * BK];
    const char* sAc = (const char*)&sA[0][0];
    const char* sBc = (const char*)&sB[0][0];

    const int tid = threadIdx.x, wid = tid >> 6, lane = tid & 63;
    const int wm = wid >> 2, wn = wid & 3;

    // bijective XCD swizzle (all grids here are multiples of 8)
    const int nwg = gridDim.x, bid = blockIdx.x;
    const int wg  = (bid & 7) * (nwg >> 3) + (bid >> 3);
    const int gx  = N / BN;
    const size_t bm = (size_t)(wg / gx) * BM;
    const size_t bn = (size_t)(wg % gx) * BN;

    f32x4 acc[8][NF] = {};

    // ---- stage source mapping (inverse swizzle on global source) ----
    // physical LDS slot of thread t (per 8KB call block): row rho=t>>2,
    // kbyte=(t&3)*16; super-row s=t>>3; logical offset = phys ^ ((s&7)<<4)
    // (XOR covers bits 4,5,6: bit 6 flips row parity within the super-row).
    const int sP   = tid >> 3;
    const int offp = (((tid >> 2) & 1) << 6) | ((tid & 3) << 4);
    const int offl = offp ^ ((sP & 7) << 4);
    const int srow = (sP << 1) | (offl >> 6);        // 0..127 per call block
    const int skel = (offl & 63) >> 1;               // source k elem 0..31
    const f16* pA = A  + (bm + srow) * (size_t)K + skel;
    const f16* pB = Bt + (bn + srow) * (size_t)K + skel;

    auto stA = [&](int b, int q, int T) {
        gload_lds16(pA + (size_t)(q * 128) * K + (size_t)T * BK,
                    (char*)sAc + b * 16384 + q * 8192 + wid * 1024);
    };
    auto stB = [&](int b, int q, int T) {
        gload_lds16(pB + (size_t)(q * 128) * K + (size_t)T * BK,
                    (char*)sBc + b * (BN * 64) + q * 8192 + wid * 1024);
    };

    // ---- fragment read offsets (swizzled), loop-invariant ----
    int offA[8], offB[NF];
    const int ks4 = (lane >> 4) << 4;                // kbyte slot 0/16/32/48
#pragma unroll
    for (int f = 0; f < 8; f++) {
        int r = wm * 128 + f * 16 + (lane & 15);
        int s = r >> 1;
        offA[f] = s * 128 + ((((r & 1) << 6) | ks4) ^ ((s & 7) << 4));
    }
#pragma unroll
    for (int n = 0; n < NF; n++) {
        int r = wn * (BN / 4) + n * 16 + (lane & 15);
        int s = r >> 1;
        offB[n] = s * 128 + ((((r & 1) << 6) | ks4) ^ ((s & 7) << 4));
    }

    const int NT = K / BK, NI = NT / 4;

    // prologue: stage tiles 0,1,2 ; wait for tile 0
    STG(0, 0) STG(1, 1) STG(2, 2)
    if constexpr (NBC == 2) { asm volatile("s_waitcnt vmcnt(8)"); }
    else                    { asm volatile("s_waitcnt vmcnt(6)"); }
    __builtin_amdgcn_s_barrier();
    asm volatile("" ::: "memory");

    for (int i = 0; i < NI - 1; ++i) {
        const int T = 4 * i;
        PHASE(0, STG(T + 3, 3), VMAIN)
        PHASE(1, STG(T + 4, 0), VMAIN)
        PHASE(2, STG(T + 5, 1), VMAIN)
        PHASE(3, STG(T + 6, 2), VMAIN)
    }
    {   // final group: tiles NT-4..NT-1; only NT-1 left to stage
        const int T = NT - 4;
        PHASE(0, STG(T + 3, 3), VMAIN)
        PHASE(1, {}, VMTAIL1)
        PHASE(2, {}, VMTAIL2)
        PHASE(3, {}, {})
    }

    // epilogue: C/D layout col=lane&15, row=(lane>>4)*4+reg  [m89-verified]
    const size_t row0 = bm + (size_t)wm * 128;
    const int col0 = (int)bn + wn * (BN / 4);
    const int c0 = lane & 15, r0 = (lane >> 4) * 4;
#pragma unroll
    for (int fm = 0; fm < 8; fm++) {
#pragma unroll
        for (int r = 0; r < 4; r++) {
            const size_t row = row0 + fm * 16 + r0 + r;
            float g = 1.0f;
            if constexpr (GATE) g = gate[row * NE];
#pragma unroll
            for (int n = 0; n < NF; n++) {
                const size_t col = (size_t)col0 + n * 16 + c0;
                float v = acc[fm][n][r] + bias[col];
                if constexpr (RELU) v = fmaxf(v, 0.0f);
                if constexpr (GATE) v *= g;
                if constexpr (OUT_F16) {
                    ((f16*)Cptr)[row * (size_t)N + col] = (f16)v;
                } else {
                    float* p = (float*)Cptr + row * (size_t)N + col;
                    *p = ACCUM ? (*p + v) : v;
                }
            }
        }
    }
}

// --------- gating head: logits = gh@gw2 + gb2, softmax -> gates fp32 -------
__global__ __launch_bounds__(256) void gate_softmax_kernel(
    const f16* __restrict__ gh, const float* __restrict__ gw2,
    const float* __restrict__ gb2, float* __restrict__ gates)
{
    const int row  = blockIdx.x * 4 + (threadIdx.x >> 6);
    const int lane = threadIdx.x & 63;
    const f16* r = gh + (size_t)row * HGD;
    float acc[NE] = {};
    for (int k = lane; k < HGD; k += 64) {
        float h = (float)r[k];
        const float* w = gw2 + (size_t)k * NE;
#pragma unroll
        for (int e = 0; e < NE; e++) acc[e] = fmaf(h, w[e], acc[e]);
    }
#pragma unroll
    for (int off = 32; off > 0; off >>= 1)
#pragma unroll
        for (int e = 0; e < NE; e++) acc[e] += __shfl_down(acc[e], off, 64);
    if (lane == 0) {
        float l[NE], m = -1e30f;
#pragma unroll
        for (int e = 0; e < NE; e++) { l[e] = acc[e] + gb2[e]; m = fmaxf(m, l[e]); }
        float s = 0.f;
#pragma unroll
        for (int e = 0; e < NE; e++) { l[e] = expf(l[e] - m); s += l[e]; }
        float inv = 1.0f / s;
#pragma unroll
        for (int e = 0; e < NE; e++) gates[(size_t)row * NE + e] = l[e] * inv;
    }
}

// ---------------------------------------------------------------------------
extern "C" void kernel_launch(void* const* d_in, const int* in_sizes, int n_in,
                              void* d_out, int out_size, void* d_ws, size_t ws_size,
                              hipStream_t stream)
{
    const float* x   = (const float*)d_in[0];
    const float* gw1 = (const float*)d_in[1];
    const float* gb1 = (const float*)d_in[2];
    const float* gw2 = (const float*)d_in[3];
    const float* gb2 = (const float*)d_in[4];
    const float* ew1 = (const float*)d_in[5];
    const float* eb1 = (const float*)d_in[6];
    const float* ew2 = (const float*)d_in[7];
    const float* eb2 = (const float*)d_in[8];
    float* out = (float*)d_out;

    // ws layout: gates(256KB) | x16(16MB) | wbuf(8MB) | hbuf(64MB, gh aliases)
    char* ws = (char*)d_ws;
    float* gates = (float*)ws;
    f16* x16  = (f16*)(ws + (256 << 10));
    f16* wbuf = x16 + (size_t)BSZ * IND;
    f16* hbuf = wbuf + (size_t)HID * IND;
    f16* gh   = hbuf;  // alias: gh fully consumed before first expert GEMM

    // 1) x -> fp16
    conv_f32_f16_kernel<<<(BSZ * IND) / (256 * 8), 256, 0, stream>>>(x, x16);

    // 2) gating GEMM1: gh = relu(x @ gw1 + gb1)   [M=8192,N=2048,K=1024]
    transpose_f32_f16_kernel<<<dim3(HGD / 64, IND / 64), 256, 0, stream>>>(gw1, wbuf, IND, HGD);
    gemm4b_kernel<256, true, false, true, false>
        <<<(HGD / 256) * (BSZ / 256), 512, 0, stream>>>(
            x16, wbuf, gb1, nullptr, gh, BSZ, HGD, IND);

    // 3) gating head + softmax -> gates
    gate_softmax_kernel<<<BSZ / 4, 256, 0, stream>>>(gh, gw2, gb2, gates);

    // 4) experts
    for (int e = 0; e < NE; e++) {
        // h = relu(x @ ew1[e] + eb1[e])   [M=8192,N=4096,K=1024]
        transpose_f32_f16_kernel<<<dim3(HID / 64, IND / 64), 256, 0, stream>>>(
            ew1 + (size_t)e * IND * HID, wbuf, IND, HID);
        gemm4b_kernel<256, true, false, true, false>
            <<<(HID / 256) * (BSZ / 256), 512, 0, stream>>>(
                x16, wbuf, eb1 + (size_t)e * HID, nullptr, hbuf, BSZ, HID, IND);

        // out (+)= gates[:,e] * (h @ ew2[e] + eb2[e])   [M=8192,N=1024,K=4096]
        transpose_f32_f16_kernel<<<dim3(OUTD / 64, HID / 64), 256, 0, stream>>>(
            ew2 + (size_t)e * HID * OUTD, wbuf, HID, OUTD);
        if (e == 0)
            gemm4b_kernel<128, false, true, false, false>
                <<<(OUTD / 128) * (BSZ / 256), 512, 0, stream>>>(
                    hbuf, wbuf, eb2 + (size_t)e * OUTD, gates + e, out, BSZ, OUTD, HID);
        else
            gemm4b_kernel<128, false, true, false, true>
                <<<(OUTD / 128) * (BSZ / 256), 512, 0, stream>>>(
                    hbuf, wbuf, eb2 + (size_t)e * OUTD, gates + e, out, BSZ, OUTD, HID);
    }
}

// Round 4
// 1380.621 us; speedup vs baseline: 1.0382x; 1.0382x over previous
//
#include <hip/hip_runtime.h>

// ---------------------------------------------------------------------------
// MoE forward: gating MLP + 8 dense experts + gate-weighted combine.
// All matmuls via mfma_f32_16x16x32_f16 (fp32 accum).
// GEMM: m201-faithful 8-phase fine-interleaved schedule. Per phase:
// {ds_read one quadrant's new frags | stage one half-tile (2 gload_lds)} ->
// barrier -> lgkmcnt(0) -> setprio(1) -> quadrant MFMA -> setprio(0) ->
// [vmcnt(6|4) at P4/P8 only] -> barrier.  Stage lands right behind the read
// front; counted vmcnt keeps 3 half-tiles in flight, never drains to 0.
// LDS swizzle: byte ^= ((row&7)<<4) within 128B rows; inverse applied to the
// global source (rule #21: gload_lds writes linearly).
// ---------------------------------------------------------------------------

#define DI __device__ __forceinline__

typedef _Float16 f16;
typedef _Float16 f16x8 __attribute__((ext_vector_type(8)));
typedef float f32x4 __attribute__((ext_vector_type(4)));

constexpr int BSZ  = 8192;
constexpr int IND  = 1024;
constexpr int HID  = 4096;
constexpr int OUTD = 1024;
constexpr int NE   = 8;
constexpr int HGD  = 2048;

// ---------------- fp32 -> fp16 vectorized convert (8 elems/thread) ---------
__global__ __launch_bounds__(256) void conv_f32_f16_kernel(
    const float* __restrict__ in, f16* __restrict__ out)
{
    size_t i = ((size_t)blockIdx.x * 256 + threadIdx.x) * 8;
    const float4* p = (const float4*)(in + i);
    float4 a = p[0], b = p[1];
    f16x8 v = {(f16)a.x, (f16)a.y, (f16)a.z, (f16)a.w,
               (f16)b.x, (f16)b.y, (f16)b.z, (f16)b.w};
    *(f16x8*)(out + i) = v;
}

// ------------- transpose + convert: W[K][N] f32 -> Wt[N][K] f16 ------------
__global__ __launch_bounds__(256) void transpose_f32_f16_kernel(
    const float* __restrict__ W, f16* __restrict__ Wt, int K, int N)
{
    __shared__ float t[64][65];
    int n0 = blockIdx.x * 64, k0 = blockIdx.y * 64;
    int tx = threadIdx.x & 63, ty = threadIdx.x >> 6;
#pragma unroll
    for (int i = 0; i < 16; i++) {
        int k = i * 4 + ty;
        t[k][tx] = W[(size_t)(k0 + k) * N + n0 + tx];
    }
    __syncthreads();
#pragma unroll
    for (int i = 0; i < 16; i++) {
        int n = i * 4 + ty;
        Wt[(size_t)(n0 + n) * K + k0 + tx] = (f16)t[tx][n];
    }
}

// ---------------- async global->LDS (16B per lane, wave-uniform dest) ------
DI void gload_lds16(const void* g, void* l)
{
    typedef const __attribute__((address_space(1))) unsigned int as1_t;
    typedef __attribute__((address_space(3))) unsigned int as3_t;
    __builtin_amdgcn_global_load_lds(
        (as1_t*)(unsigned long long)(__SIZE_TYPE__)g,
        (as3_t*)(unsigned int)(__SIZE_TYPE__)l,
        16, 0, 0);
}

// sync building blocks (rule #18: sched_barrier after lgkmcnt before MFMA)
#define SYNC_HEAD                                                              \
    __builtin_amdgcn_sched_barrier(0);                                         \
    __builtin_amdgcn_s_barrier();                                              \
    asm volatile("s_waitcnt lgkmcnt(0)" ::: "memory");                         \
    __builtin_amdgcn_sched_barrier(0);
#define SYNC_HEAD_T8                                                           \
    __builtin_amdgcn_sched_barrier(0);                                         \
    asm volatile("s_waitcnt lgkmcnt(8)");                                      \
    __builtin_amdgcn_s_barrier();                                              \
    asm volatile("s_waitcnt lgkmcnt(0)" ::: "memory");                         \
    __builtin_amdgcn_sched_barrier(0);
#define SYNC_TAIL                                                              \
    __builtin_amdgcn_sched_barrier(0);                                         \
    __builtin_amdgcn_s_barrier();                                              \
    asm volatile("" ::: "memory");

// ---------------------------------------------------------------------------
// Big kernel: BM=256, BN=256, BK=64, 8 waves 2Mx4N (wave tile 128x64).
// Phases per K-tile: (mh0,nh0):12rd, (mh0,nh1):4rd, (mh1,nh1):8rd, (mh1,nh0):0rd.
// Stage points (2 calls each): P1:A13(t+1,b1) P2:A02(t+2,b0) P3:B01(t+2)
// P4:B23(t+2)+vm6 P5:A13(t+2) P6:A02(t+3,b1) P7:B01(t+3) P8:B23(t+3)+vm6.
// FIFO-verified: every read covered by a prior vmcnt(6)+barrier; every
// overwrite >=1 barrier after the region's last read.
// ---------------------------------------------------------------------------
template <bool RELU>
__global__ __launch_bounds__(512, 2) void gemm256_kernel(
    const f16* __restrict__ A, const f16* __restrict__ Bt,
    const float* __restrict__ bias, f16* __restrict__ Cptr,
    int M, int N, int K)
{
    constexpr int BM = 256, BN = 256, BK = 64;
    constexpr int AT = BM * BK * 2, BT = BN * BK * 2;   // 32768 each
    __shared__ __align__(16) f16 sA[2][BM * BK];
    __shared__ __align__(16) f16 sB[2][BN * BK];
    const char* sAc = (const char*)sA;
    const char* sBc = (const char*)sB;

    const int tid = threadIdx.x, wid = tid >> 6, lane = tid & 63;
    const int wm = wid >> 2, wn = wid & 3;
    const int nwg = gridDim.x, bid = blockIdx.x;
    const int wg = (bid & 7) * (nwg >> 3) + (bid >> 3);
    const int gx = N / BN;
    const size_t bm = (size_t)(wg / gx) * BM;
    const size_t bn = (size_t)(wg % gx) * BN;

    f32x4 acc[8][4] = {};

    // stage source: thread covers (row rho, phys 16B slot); source col is the
    // inverse-swizzled logical slot.
    const int rho  = tid >> 3;
    const int slot = (((tid & 7) << 4) ^ (((tid >> 3) & 7) << 4));
    const f16* pA = A  + (bm + rho) * (size_t)K + (slot >> 1);
    const f16* pB = Bt + (bn + rho) * (size_t)K + (slot >> 1);

    auto stA = [&](int b, int q, int T) {
        gload_lds16(pA + ((size_t)q * 64) * K + (size_t)T * BK,
                    (char*)sAc + b * AT + q * 8192 + wid * 1024);
    };
    auto stB = [&](int b, int q, int T) {
        gload_lds16(pB + ((size_t)q * 64) * K + (size_t)T * BK,
                    (char*)sBc + b * BT + q * 8192 + wid * 1024);
    };

    // fragment read offsets (swizzled); kc toggles byte bit 6
    int offA0[8], offB0[4];
#pragma unroll
    for (int f = 0; f < 8; f++) {
        int r = wm * 128 + f * 16 + (lane & 15);
        offA0[f] = r * 128 + ((((lane >> 4) << 4)) ^ ((r & 7) << 4));
    }
#pragma unroll
    for (int f = 0; f < 4; f++) {
        int r = wn * 64 + f * 16 + (lane & 15);
        offB0[f] = r * 128 + ((((lane >> 4) << 4)) ^ ((r & 7) << 4));
    }

    f16x8 av[4][2], bv0[2][2], bv1[2][2];

#define LDAQ(B, MH)                                                            \
    _Pragma("unroll") for (int f = 0; f < 4; f++)                              \
    _Pragma("unroll") for (int kc = 0; kc < 2; kc++)                           \
        av[f][kc] = *(const f16x8*)(sAc + (B) * AT + (offA0[(MH)*4+f] ^ (kc << 6)));
#define LDBH(B, NH, BV)                                                        \
    _Pragma("unroll") for (int f = 0; f < 2; f++)                              \
    _Pragma("unroll") for (int kc = 0; kc < 2; kc++)                           \
        BV[f][kc] = *(const f16x8*)(sBc + (B) * BT + (offB0[(NH)*2+f] ^ (kc << 6)));
#define QUAD(MH, NH, BV)                                                       \
    __builtin_amdgcn_s_setprio(1);                                             \
    _Pragma("unroll") for (int f = 0; f < 4; f++)                              \
    _Pragma("unroll") for (int g = 0; g < 2; g++)                              \
    _Pragma("unroll") for (int kc = 0; kc < 2; kc++)                           \
        acc[(MH)*4+f][(NH)*2+g] = __builtin_amdgcn_mfma_f32_16x16x32_f16(      \
            av[f][kc], BV[g][kc], acc[(MH)*4+f][(NH)*2+g], 0, 0, 0);           \
    __builtin_amdgcn_s_setprio(0);

    const int NT = K / BK, NI = NT / 2;

    // prologue: tile0 full + tile1 minus A13
    stA(0,0,0); stA(0,2,0); stB(0,0,0); stB(0,1,0); stB(0,2,0); stB(0,3,0);
    stA(0,1,0); stA(0,3,0);
    stA(1,0,1); stA(1,2,1); stB(1,0,1); stB(1,1,1); stB(1,2,1); stB(1,3,1);
    asm volatile("s_waitcnt vmcnt(6)");
    __builtin_amdgcn_s_barrier();
    asm volatile("" ::: "memory");

    for (int i = 0; i < NI - 1; ++i) {
        const int t = 2 * i;
        LDAQ(0, 0) LDBH(0, 0, bv0)
        stA(1, 1, t + 1); stA(1, 3, t + 1);
        SYNC_HEAD_T8
        QUAD(0, 0, bv0)
        SYNC_TAIL
        LDBH(0, 1, bv1)
        stA(0, 0, t + 2); stA(0, 2, t + 2);
        SYNC_HEAD
        QUAD(0, 1, bv1)
        SYNC_TAIL
        LDAQ(0, 1)
        stB(0, 0, t + 2); stB(0, 1, t + 2);
        SYNC_HEAD
        QUAD(1, 1, bv1)
        SYNC_TAIL
        stB(0, 2, t + 2); stB(0, 3, t + 2);
        SYNC_HEAD
        QUAD(1, 0, bv0)
        asm volatile("s_waitcnt vmcnt(6)");
        SYNC_TAIL
        LDAQ(1, 0) LDBH(1, 0, bv0)
        stA(0, 1, t + 2); stA(0, 3, t + 2);
        SYNC_HEAD_T8
        QUAD(0, 0, bv0)
        SYNC_TAIL
        LDBH(1, 1, bv1)
        stA(1, 0, t + 3); stA(1, 2, t + 3);
        SYNC_HEAD
        QUAD(0, 1, bv1)
        SYNC_TAIL
        LDAQ(1, 1)
        stB(1, 0, t + 3); stB(1, 1, t + 3);
        SYNC_HEAD
        QUAD(1, 1, bv1)
        SYNC_TAIL
        stB(1, 2, t + 3); stB(1, 3, t + 3);
        SYNC_HEAD
        QUAD(1, 0, bv0)
        asm volatile("s_waitcnt vmcnt(6)");
        SYNC_TAIL
    }
    {   // final iteration (tiles NT-2, NT-1)
        LDAQ(0, 0) LDBH(0, 0, bv0)
        stA(1, 1, NT - 1); stA(1, 3, NT - 1);
        SYNC_HEAD_T8
        QUAD(0, 0, bv0)
        SYNC_TAIL
        LDBH(0, 1, bv1)
        SYNC_HEAD
        QUAD(0, 1, bv1)
        SYNC_TAIL
        LDAQ(0, 1)
        SYNC_HEAD
        QUAD(1, 1, bv1)
        SYNC_TAIL
        SYNC_HEAD
        QUAD(1, 0, bv0)
        asm volatile("s_waitcnt vmcnt(0)");
        SYNC_TAIL
        LDAQ(1, 0) LDBH(1, 0, bv0)
        SYNC_HEAD
        QUAD(0, 0, bv0)
        SYNC_TAIL
        LDBH(1, 1, bv1)
        SYNC_HEAD
        QUAD(0, 1, bv1)
        SYNC_TAIL
        LDAQ(1, 1)
        SYNC_HEAD
        QUAD(1, 1, bv1)
        SYNC_TAIL
        SYNC_HEAD
        QUAD(1, 0, bv0)
        SYNC_TAIL
    }
#undef LDAQ
#undef LDBH
#undef QUAD

    // epilogue: C/D layout col=lane&15, row=(lane>>4)*4+reg
    const size_t row0 = bm + (size_t)wm * 128;
    const int col0 = (int)bn + wn * 64;
    const int c0 = lane & 15, r0 = (lane >> 4) * 4;
#pragma unroll
    for (int fm = 0; fm < 8; fm++)
#pragma unroll
        for (int r = 0; r < 4; r++) {
            const size_t row = row0 + fm * 16 + r0 + r;
#pragma unroll
            for (int n = 0; n < 4; n++) {
                const size_t col = (size_t)col0 + n * 16 + c0;
                float v = acc[fm][n][r] + bias[col];
                if constexpr (RELU) v = fmaxf(v, 0.0f);
                Cptr[row * (size_t)N + col] = (f16)v;
            }
        }
}

// ---------------------------------------------------------------------------
// OUT kernel: BM=256, BN=128, BK=64, 8 waves 2Mx4N (wave tile 128x32).
// Phases per K-tile: (mh,kc) pairs, 8 MFMA each; reads 8/4/4/4.
// Stage points: P1:A13(t+1,b1) P3:A02(t+2,b0) P4:B(t+2)+vm4 P5:A13(t+2)
// P7:A02(t+3,b1) P8:B(t+3)+vm4.  FIFO-verified with vmcnt(4).
// ---------------------------------------------------------------------------
template <bool ACCUM>
__global__ __launch_bounds__(512, 2) void gemmO_kernel(
    const f16* __restrict__ A, const f16* __restrict__ Bt,
    const float* __restrict__ bias, const float* __restrict__ gate,
    float* __restrict__ Cptr, int M, int N, int K)
{
    constexpr int BM = 256, BN = 128, BK = 64;
    constexpr int AT = BM * BK * 2, BT = BN * BK * 2;   // 32768 / 16384
    __shared__ __align__(16) f16 sA[2][BM * BK];
    __shared__ __align__(16) f16 sB[2][BN * BK];
    const char* sAc = (const char*)sA;
    const char* sBc = (const char*)sB;

    const int tid = threadIdx.x, wid = tid >> 6, lane = tid & 63;
    const int wm = wid >> 2, wn = wid & 3;
    const int nwg = gridDim.x, bid = blockIdx.x;
    const int wg = (bid & 7) * (nwg >> 3) + (bid >> 3);
    const int gx = N / BN;
    const size_t bm = (size_t)(wg / gx) * BM;
    const size_t bn = (size_t)(wg % gx) * BN;

    f32x4 acc[8][2] = {};

    const int rho  = tid >> 3;
    const int slot = (((tid & 7) << 4) ^ (((tid >> 3) & 7) << 4));
    const f16* pA = A  + (bm + rho) * (size_t)K + (slot >> 1);
    const f16* pB = Bt + (bn + rho) * (size_t)K + (slot >> 1);

    auto stA = [&](int b, int q, int T) {
        gload_lds16(pA + ((size_t)q * 64) * K + (size_t)T * BK,
                    (char*)sAc + b * AT + q * 8192 + wid * 1024);
    };
    auto stB = [&](int b, int q, int T) {
        gload_lds16(pB + ((size_t)q * 64) * K + (size_t)T * BK,
                    (char*)sBc + b * BT + q * 8192 + wid * 1024);
    };

    int offA0[8], offB0[2];
#pragma unroll
    for (int f = 0; f < 8; f++) {
        int r = wm * 128 + f * 16 + (lane & 15);
        offA0[f] = r * 128 + ((((lane >> 4) << 4)) ^ ((r & 7) << 4));
    }
#pragma unroll
    for (int f = 0; f < 2; f++) {
        int r = wn * 32 + f * 16 + (lane & 15);
        offB0[f] = r * 128 + ((((lane >> 4) << 4)) ^ ((r & 7) << 4));
    }

    f16x8 av[4], bv[2][2];

#define LDA4(B, MH, KC)                                                        \
    _Pragma("unroll") for (int f = 0; f < 4; f++)                              \
        av[f] = *(const f16x8*)(sAc + (B) * AT + (offA0[(MH)*4+f] ^ ((KC) << 6)));
#define LDBA(B)                                                                \
    _Pragma("unroll") for (int f = 0; f < 2; f++)                              \
    _Pragma("unroll") for (int kc = 0; kc < 2; kc++)                           \
        bv[f][kc] = *(const f16x8*)(sBc + (B) * BT + (offB0[f] ^ (kc << 6)));
#define OCT(MH, KC)                                                            \
    __builtin_amdgcn_s_setprio(1);                                             \
    _Pragma("unroll") for (int f = 0; f < 4; f++)                              \
    _Pragma("unroll") for (int g = 0; g < 2; g++)                              \
        acc[(MH)*4+f][g] = __builtin_amdgcn_mfma_f32_16x16x32_f16(             \
            av[f], bv[g][KC], acc[(MH)*4+f][g], 0, 0, 0);                      \
    __builtin_amdgcn_s_setprio(0);

    const int NT = K / BK, NI = NT / 2;

    stA(0,0,0); stA(0,2,0); stB(0,0,0); stB(0,1,0); stA(0,1,0); stA(0,3,0);
    stA(1,0,1); stA(1,2,1); stB(1,0,1); stB(1,1,1);
    asm volatile("s_waitcnt vmcnt(4)");
    __builtin_amdgcn_s_barrier();
    asm volatile("" ::: "memory");

    for (int i = 0; i < NI - 1; ++i) {
        const int t = 2 * i;
        LDA4(0, 0, 0) LDBA(0)
        stA(1, 1, t + 1); stA(1, 3, t + 1);
        SYNC_HEAD
        OCT(0, 0)
        SYNC_TAIL
        LDA4(0, 0, 1)
        SYNC_HEAD
        OCT(0, 1)
        SYNC_TAIL
        LDA4(0, 1, 0)
        stA(0, 0, t + 2); stA(0, 2, t + 2);
        SYNC_HEAD
        OCT(1, 0)
        SYNC_TAIL
        LDA4(0, 1, 1)
        stB(0, 0, t + 2); stB(0, 1, t + 2);
        SYNC_HEAD
        OCT(1, 1)
        asm volatile("s_waitcnt vmcnt(4)");
        SYNC_TAIL
        LDA4(1, 0, 0) LDBA(1)
        stA(0, 1, t + 2); stA(0, 3, t + 2);
        SYNC_HEAD
        OCT(0, 0)
        SYNC_TAIL
        LDA4(1, 0, 1)
        SYNC_HEAD
        OCT(0, 1)
        SYNC_TAIL
        LDA4(1, 1, 0)
        stA(1, 0, t + 3); stA(1, 2, t + 3);
        SYNC_HEAD
        OCT(1, 0)
        SYNC_TAIL
        LDA4(1, 1, 1)
        stB(1, 0, t + 3); stB(1, 1, t + 3);
        SYNC_HEAD
        OCT(1, 1)
        asm volatile("s_waitcnt vmcnt(4)");
        SYNC_TAIL
    }
    {   // final iteration
        LDA4(0, 0, 0) LDBA(0)
        stA(1, 1, NT - 1); stA(1, 3, NT - 1);
        SYNC_HEAD
        OCT(0, 0)
        SYNC_TAIL
        LDA4(0, 0, 1)
        SYNC_HEAD
        OCT(0, 1)
        SYNC_TAIL
        LDA4(0, 1, 0)
        SYNC_HEAD
        OCT(1, 0)
        SYNC_TAIL
        LDA4(0, 1, 1)
        SYNC_HEAD
        OCT(1, 1)
        asm volatile("s_waitcnt vmcnt(0)");
        SYNC_TAIL
        LDA4(1, 0, 0) LDBA(1)
        SYNC_HEAD
        OCT(0, 0)
        SYNC_TAIL
        LDA4(1, 0, 1)
        SYNC_HEAD
        OCT(0, 1)
        SYNC_TAIL
        LDA4(1, 1, 0)
        SYNC_HEAD
        OCT(1, 0)
        SYNC_TAIL
        LDA4(1, 1, 1)
        SYNC_HEAD
        OCT(1, 1)
        SYNC_TAIL
    }
#undef LDA4
#undef LDBA
#undef OCT

    const size_t row0 = bm + (size_t)wm * 128;
    const int col0 = (int)bn + wn * 32;
    const int c0 = lane & 15, r0 = (lane >> 4) * 4;
#pragma unroll
    for (int fm = 0; fm < 8; fm++)
#pragma unroll
        for (int r = 0; r < 4; r++) {
            const size_t row = row0 + fm * 16 + r0 + r;
            const float g = gate[row * NE];
#pragma unroll
            for (int n = 0; n < 2; n++) {
                const size_t col = (size_t)col0 + n * 16 + c0;
                float v = (acc[fm][n][r] + bias[col]) * g;
                float* p = Cptr + row * (size_t)N + col;
                *p = ACCUM ? (*p + v) : v;
            }
        }
}

// --------- gating head: logits = gh@gw2 + gb2, softmax -> gates fp32 -------
__global__ __launch_bounds__(256) void gate_softmax_kernel(
    const f16* __restrict__ gh, const float* __restrict__ gw2,
    const float* __restrict__ gb2, float* __restrict__ gates)
{
    const int row  = blockIdx.x * 4 + (threadIdx.x >> 6);
    const int lane = threadIdx.x & 63;
    const f16* r = gh + (size_t)row * HGD;
    float acc[NE] = {};
    for (int k = lane; k < HGD; k += 64) {
        float h = (float)r[k];
        const float* w = gw2 + (size_t)k * NE;
#pragma unroll
        for (int e = 0; e < NE; e++) acc[e] = fmaf(h, w[e], acc[e]);
    }
#pragma unroll
    for (int off = 32; off > 0; off >>= 1)
#pragma unroll
        for (int e = 0; e < NE; e++) acc[e] += __shfl_down(acc[e], off, 64);
    if (lane == 0) {
        float l[NE], m = -1e30f;
#pragma unroll
        for (int e = 0; e < NE; e++) { l[e] = acc[e] + gb2[e]; m = fmaxf(m, l[e]); }
        float s = 0.f;
#pragma unroll
        for (int e = 0; e < NE; e++) { l[e] = expf(l[e] - m); s += l[e]; }
        float inv = 1.0f / s;
#pragma unroll
        for (int e = 0; e < NE; e++) gates[(size_t)row * NE + e] = l[e] * inv;
    }
}

// ---------------------------------------------------------------------------
extern "C" void kernel_launch(void* const* d_in, const int* in_sizes, int n_in,
                              void* d_out, int out_size, void* d_ws, size_t ws_size,
                              hipStream_t stream)
{
    const float* x   = (const float*)d_in[0];
    const float* gw1 = (const float*)d_in[1];
    const float* gb1 = (const float*)d_in[2];
    const float* gw2 = (const float*)d_in[3];
    const float* gb2 = (const float*)d_in[4];
    const float* ew1 = (const float*)d_in[5];
    const float* eb1 = (const float*)d_in[6];
    const float* ew2 = (const float*)d_in[7];
    const float* eb2 = (const float*)d_in[8];
    float* out = (float*)d_out;

    // ws layout: gates(256KB) | x16(16MB) | wbuf(8MB) | hbuf(64MB, gh aliases)
    char* ws = (char*)d_ws;
    float* gates = (float*)ws;
    f16* x16  = (f16*)(ws + (256 << 10));
    f16* wbuf = x16 + (size_t)BSZ * IND;
    f16* hbuf = wbuf + (size_t)HID * IND;
    f16* gh   = hbuf;  // alias: gh fully consumed before first expert GEMM

    // 1) x -> fp16
    conv_f32_f16_kernel<<<(BSZ * IND) / (256 * 8), 256, 0, stream>>>(x, x16);

    // 2) gating GEMM1: gh = relu(x @ gw1 + gb1)   [M=8192,N=2048,K=1024]
    transpose_f32_f16_kernel<<<dim3(HGD / 64, IND / 64), 256, 0, stream>>>(gw1, wbuf, IND, HGD);
    gemm256_kernel<true>
        <<<(HGD / 256) * (BSZ / 256), 512, 0, stream>>>(
            x16, wbuf, gb1, gh, BSZ, HGD, IND);

    // 3) gating head + softmax -> gates
    gate_softmax_kernel<<<BSZ / 4, 256, 0, stream>>>(gh, gw2, gb2, gates);

    // 4) experts
    for (int e = 0; e < NE; e++) {
        // h = relu(x @ ew1[e] + eb1[e])   [M=8192,N=4096,K=1024]
        transpose_f32_f16_kernel<<<dim3(HID / 64, IND / 64), 256, 0, stream>>>(
            ew1 + (size_t)e * IND * HID, wbuf, IND, HID);
        gemm256_kernel<true>
            <<<(HID / 256) * (BSZ / 256), 512, 0, stream>>>(
                x16, wbuf, eb1 + (size_t)e * HID, hbuf, BSZ, HID, IND);

        // out (+)= gates[:,e] * (h @ ew2[e] + eb2[e])   [M=8192,N=1024,K=4096]
        transpose_f32_f16_kernel<<<dim3(OUTD / 64, HID / 64), 256, 0, stream>>>(
            ew2 + (size_t)e * HID * OUTD, wbuf, HID, OUTD);
        if (e == 0)
            gemmO_kernel<false>
                <<<(OUTD / 128) * (BSZ / 256), 512, 0, stream>>>(
                    hbuf, wbuf, eb2 + (size_t)e * OUTD, gates + e, out, BSZ, OUTD, HID);
        else
            gemmO_kernel<true>
                <<<(OUTD / 128) * (BSZ / 256), 512, 0, stream>>>(
                    hbuf, wbuf, eb2 + (size_t)e * OUTD, gates + e, out, BSZ, OUTD, HID);
    }
}